// Round 10
// baseline (662.088 us; speedup 1.0000x reference)
//
#include <hip/hip_runtime.h>
#include <math.h>

// Problem constants (B,C,H,W fixed by the reference)
#define BB 4
#define CC 16
#define HH 256
#define WW 256
#define NN (HH*WW)        // 65536 pixels per batch
#define MM 256            // superpixels
#define CROW 20           // padded center row: c[0..17], [18]=||c||^2, [19]=pad
#define PROW 20           // pixel row: p[0..17], [18]=||p||^2, [19]=1.0
#define PIX 32            // pixels per sub-tile
#define TSUB 4            // sub-tiles per block (128 px/block)
#define PIXPERBLK (PIX*TSUB)
#define CHUNKS (NN/PIXPERBLK)   // 512 chunks per batch

typedef float f32x2 __attribute__((ext_vector_type(2)));

__device__ __forceinline__ f32x2 mk2(float a, float b) { f32x2 r; r.x = a; r.y = b; return r; }
// Packed fp32 FMA: lowers to v_pk_fma_f32 (VOP3P) — 2 lanes of f32 per instr.
__device__ __forceinline__ f32x2 pk_fma(f32x2 a, f32x2 b, f32x2 c) {
    return __builtin_elementwise_fma(a, b, c);
}

// ---------------------------------------------------------------------------
// Initial centers: 16x16 block means of features + analytic xy means + ||c||^2
// ---------------------------------------------------------------------------
__global__ void init_centers(const float* __restrict__ feat, float* __restrict__ cbuf)
{
    const int b    = blockIdx.x >> 8;
    const int m    = blockIdx.x & 255;
    const int lane = threadIdx.x;          // 0..63
    const int sy = m >> 4, sx = m & 15;

    float cvals[16];
#pragma unroll
    for (int d = 0; d < 16; ++d) {
        float v = 0.f;
#pragma unroll
        for (int k = 0; k < 4; ++k) {
            int q  = lane + (k << 6);            // 0..255 within 16x16 block
            int py = q >> 4, px = q & 15;
            int n  = (sy*16 + py)*WW + sx*16 + px;
            v += feat[((b*CC + d) << 16) + n];
        }
#pragma unroll
        for (int off = 32; off; off >>= 1) v += __shfl_down(v, off);
        cvals[d] = v * (1.f/256.f);
    }
    if (lane == 0) {
        float* row = cbuf + (b*MM + m)*CROW;
        float cn2 = 0.f;
#pragma unroll
        for (int d = 0; d < 16; ++d) { row[d] = cvals[d]; cn2 = fmaf(cvals[d], cvals[d], cn2); }
        float cx = (sx*16 + 7.5f) * (1.f/256.f);
        float cy = (sy*16 + 7.5f) * (1.f/256.f);
        row[16] = cx; row[17] = cy;
        cn2 = fmaf(cx, cx, cn2);
        cn2 = fmaf(cy, cy, cn2);
        row[18] = cn2;
        row[19] = 0.f;
    }
}

// ---------------------------------------------------------------------------
// Pre-transpose: pixel rows {p[0..17], ||p||^2, 1.0} into contiguous
// ptbuf[b][n][20] in d_ws.
// ---------------------------------------------------------------------------
__global__ void build_pt(const float* __restrict__ feat, float* __restrict__ ptbuf)
{
    const int b = blockIdx.x >> 8;
    const int n = ((blockIdx.x & 255) << 8) | threadIdx.x;
    float v[16];
#pragma unroll
    for (int d = 0; d < 16; ++d) v[d] = feat[((b*CC + d) << 16) + n];
    float x = (float)(n & 255) * (1.f/256.f);
    float y = (float)(n >> 8) * (1.f/256.f);
    float pn2 = 0.f;
#pragma unroll
    for (int d = 0; d < 16; ++d) pn2 = fmaf(v[d], v[d], pn2);
    pn2 = fmaf(x, x, pn2);
    pn2 = fmaf(y, y, pn2);
    float4* row = reinterpret_cast<float4*>(ptbuf + (size_t)(b*NN + n)*PROW);
    row[0] = make_float4(v[0],  v[1],  v[2],  v[3]);
    row[1] = make_float4(v[4],  v[5],  v[6],  v[7]);
    row[2] = make_float4(v[8],  v[9],  v[10], v[11]);
    row[3] = make_float4(v[12], v[13], v[14], v[15]);
    row[4] = make_float4(x, y, pn2, 1.0f);
}

// ---------------------------------------------------------------------------
// Fused iteration kernel, KM=4: lane L of wave wv handles the 4 centers
// m = wv*64 + (L>>2) + 16j (j=0..3) over 8 pixels px = (L&3) + 4k — each LDS
// p-row read amortized over 4 dots/accumulates (LDS write-back is the
// measured bottleneck; reads per wave halve vs KM=2).
// px interleave (L&3 + 4k) puts the wave's 4 distinct ds_read addresses
// 20 dwords apart -> disjoint bank quads, no conflicts.
// Softmax: intra-wave 16-lane reduce-scatter -> per-wave partial in ssum_s,
// cross-wave combine via tid<32 (2 barriers/subtile).
// Non-final partial combine: 2-round shuffle reduce-scatter over lanes
// L^1, L^2 (the px-group partners) -> each thread stores exactly 1 pp row.
// ---------------------------------------------------------------------------
template<bool FINAL>
__global__ __launch_bounds__(256, 2)
void ssn_iter(const float* __restrict__ ptbuf, const float* __restrict__ cbuf,
              float* __restrict__ wout)   // pp (non-final) or Q (final)
{
    __shared__ __align__(16) float pls[PIXPERBLK*PROW];   // 10240 B
    __shared__ float ssum_s[TSUB][4][PIX];                //  2048 B
    __shared__ float w_s[TSUB][PIX];                      //   512 B

    const int tid    = threadIdx.x;
    const int b      = blockIdx.x >> 9;
    const int chunk  = blockIdx.x & (CHUNKS-1);
    const int n_base = chunk * PIXPERBLK;
    const int L      = tid & 63;
    const int wv     = tid >> 6;
    const int g      = L & 3;              // px group: px = g + 4k
    const int msub   = L >> 2;             // 0..15
    const int mbase  = wv*64 + msub;       // m_j = mbase + 16*j

    // ---- stage 128 rows x 80 B = 640 float4, fully coalesced & contiguous ----
    {
        const float4* src = reinterpret_cast<const float4*>(
            ptbuf + (size_t)(b*NN + n_base)*PROW);
#pragma unroll
        for (int k = 0; k < 3; ++k) {
            int f = tid + (k << 8);
            if (f < PIXPERBLK*PROW/4)
                reinterpret_cast<float4*>(pls)[f] = src[f];
        }
    }

    // center registers for 4 m's, packed pairs
    f32x2 cp[4][9]; float cn2[4];
#pragma unroll
    for (int j = 0; j < 4; ++j) {
        const float4* cv = reinterpret_cast<const float4*>(
            cbuf + (b*MM + mbase + 16*j)*CROW);
        float4 a0 = cv[0], a1 = cv[1], a2 = cv[2], a3 = cv[3], a4 = cv[4];
        cp[j][0]=mk2(a0.x,a0.y); cp[j][1]=mk2(a0.z,a0.w);
        cp[j][2]=mk2(a1.x,a1.y); cp[j][3]=mk2(a1.z,a1.w);
        cp[j][4]=mk2(a2.x,a2.y); cp[j][5]=mk2(a2.z,a2.w);
        cp[j][6]=mk2(a3.x,a3.y); cp[j][7]=mk2(a3.z,a3.w);
        cp[j][8]=mk2(a4.x,a4.y); cn2[j]=a4.z;
    }

    f32x2 acc[4][9]; float accd[4];
    if (!FINAL) {
#pragma unroll
        for (int j = 0; j < 4; ++j) {
#pragma unroll
            for (int d = 0; d < 9; ++d) acc[j][d] = mk2(0.f, 0.f);
            accd[j] = 0.f;
        }
    }

    __syncthreads();   // pls ready

    for (int t = 0; t < TSUB; ++t) {
        // ---- phase 1: e[j][k] = exp(-dist(px_k, m_j)); 1 row read -> 4 dots ----
        float e[4][8];
#pragma unroll
        for (int k = 0; k < 8; ++k) {
            const int row = t*PIX + g + 4*k;
            const float4* pv = reinterpret_cast<const float4*>(&pls[row*PROW]);
            float4 q0 = pv[0], q1 = pv[1], q2 = pv[2], q3 = pv[3], q4 = pv[4];
            f32x2 u0=mk2(q0.x,q0.y), u1=mk2(q0.z,q0.w), u2=mk2(q1.x,q1.y),
                  u3=mk2(q1.z,q1.w), u4=mk2(q2.x,q2.y), u5=mk2(q2.z,q2.w),
                  u6=mk2(q3.x,q3.y), u7=mk2(q3.z,q3.w), u8=mk2(q4.x,q4.y);
            f32x2 d0=mk2(0.f,0.f), d1=mk2(0.f,0.f), d2v=mk2(0.f,0.f), d3=mk2(0.f,0.f);
            d0 = pk_fma(u0, cp[0][0], d0); d1 = pk_fma(u0, cp[1][0], d1);
            d2v= pk_fma(u0, cp[2][0], d2v);d3 = pk_fma(u0, cp[3][0], d3);
            d0 = pk_fma(u1, cp[0][1], d0); d1 = pk_fma(u1, cp[1][1], d1);
            d2v= pk_fma(u1, cp[2][1], d2v);d3 = pk_fma(u1, cp[3][1], d3);
            d0 = pk_fma(u2, cp[0][2], d0); d1 = pk_fma(u2, cp[1][2], d1);
            d2v= pk_fma(u2, cp[2][2], d2v);d3 = pk_fma(u2, cp[3][2], d3);
            d0 = pk_fma(u3, cp[0][3], d0); d1 = pk_fma(u3, cp[1][3], d1);
            d2v= pk_fma(u3, cp[2][3], d2v);d3 = pk_fma(u3, cp[3][3], d3);
            d0 = pk_fma(u4, cp[0][4], d0); d1 = pk_fma(u4, cp[1][4], d1);
            d2v= pk_fma(u4, cp[2][4], d2v);d3 = pk_fma(u4, cp[3][4], d3);
            d0 = pk_fma(u5, cp[0][5], d0); d1 = pk_fma(u5, cp[1][5], d1);
            d2v= pk_fma(u5, cp[2][5], d2v);d3 = pk_fma(u5, cp[3][5], d3);
            d0 = pk_fma(u6, cp[0][6], d0); d1 = pk_fma(u6, cp[1][6], d1);
            d2v= pk_fma(u6, cp[2][6], d2v);d3 = pk_fma(u6, cp[3][6], d3);
            d0 = pk_fma(u7, cp[0][7], d0); d1 = pk_fma(u7, cp[1][7], d1);
            d2v= pk_fma(u7, cp[2][7], d2v);d3 = pk_fma(u7, cp[3][7], d3);
            d0 = pk_fma(u8, cp[0][8], d0); d1 = pk_fma(u8, cp[1][8], d1);
            d2v= pk_fma(u8, cp[2][8], d2v);d3 = pk_fma(u8, cp[3][8], d3);
            float s0 = fmaf(-2.f, d0.x + d0.y, q4.z + cn2[0]);
            float s1 = fmaf(-2.f, d1.x + d1.y, q4.z + cn2[1]);
            float s2 = fmaf(-2.f, d2v.x + d2v.y, q4.z + cn2[2]);
            float s3 = fmaf(-2.f, d3.x + d3.y, q4.z + cn2[3]);
            e[0][k] = __expf(-__builtin_amdgcn_sqrtf(fmaxf(s0, 1e-12f)));
            e[1][k] = __expf(-__builtin_amdgcn_sqrtf(fmaxf(s1, 1e-12f)));
            e[2][k] = __expf(-__builtin_amdgcn_sqrtf(fmaxf(s2, 1e-12f)));
            e[3][k] = __expf(-__builtin_amdgcn_sqrtf(fmaxf(s3, 1e-12f)));
        }

        // ---- intra-wave softmax partial: 16-lane reduce-scatter over 8 px ----
        float s[8];
#pragma unroll
        for (int k = 0; k < 8; ++k)
            s[k] = (e[0][k] + e[1][k]) + (e[2][k] + e[3][k]);
#define RS_ROUND(MASK, H) { const bool hi = (L & (MASK)); \
        _Pragma("unroll") \
        for (int k = 0; k < (H); ++k) { \
            float a = s[k], bq = s[k+(H)]; \
            float recv = __shfl_xor(hi ? a : bq, (MASK)); \
            s[k] = (hi ? bq : a) + recv; } }
        RS_ROUND(4, 4)
        RS_ROUND(8, 2)
        RS_ROUND(16, 1)
#undef RS_ROUND
        s[0] += __shfl_xor(s[0], 32);
        {
            const int kown = (((L>>2)&1)<<2) | (((L>>3)&1)<<1) | ((L>>4)&1);
            if (L < 32) ssum_s[t][wv][g + 4*kown] = s[0];
        }
        __syncthreads();
        if (tid < 32) {
            w_s[t][tid] = 1.0f / (ssum_s[t][0][tid] + ssum_s[t][1][tid]
                                + ssum_s[t][2][tid] + ssum_s[t][3][tid]);
        }
        __syncthreads();

        // ---- phase 2 ----
        if (FINAL) {
#pragma unroll
            for (int k = 0; k < 8; ++k) {
                float w = w_s[t][g + 4*k];
                size_t rowoff = ((size_t)(b*NN + n_base + t*PIX + g + 4*k)) << 8;
#pragma unroll
                for (int j = 0; j < 4; ++j)
                    wout[rowoff + mbase + 16*j] = e[j][k] * w;
            }
        } else {
#pragma unroll
            for (int k = 0; k < 8; ++k) {
                const int row = t*PIX + g + 4*k;
                const float4* pv = reinterpret_cast<const float4*>(&pls[row*PROW]);
                float4 q0 = pv[0], q1 = pv[1], q2 = pv[2], q3 = pv[3];
                float2 xy = *reinterpret_cast<const float2*>(&pls[row*PROW + 16]);
                float w = w_s[t][g + 4*k];
                f32x2 u0=mk2(q0.x,q0.y), u1=mk2(q0.z,q0.w), u2=mk2(q1.x,q1.y),
                      u3=mk2(q1.z,q1.w), u4=mk2(q2.x,q2.y), u5=mk2(q2.z,q2.w),
                      u6=mk2(q3.x,q3.y), u7=mk2(q3.z,q3.w), u8=mk2(xy.x,xy.y);
#pragma unroll
                for (int j = 0; j < 4; ++j) {
                    float ew = e[j][k] * w;
                    f32x2 ew2 = mk2(ew, ew);
                    acc[j][0] = pk_fma(ew2, u0, acc[j][0]);
                    acc[j][1] = pk_fma(ew2, u1, acc[j][1]);
                    acc[j][2] = pk_fma(ew2, u2, acc[j][2]);
                    acc[j][3] = pk_fma(ew2, u3, acc[j][3]);
                    acc[j][4] = pk_fma(ew2, u4, acc[j][4]);
                    acc[j][5] = pk_fma(ew2, u5, acc[j][5]);
                    acc[j][6] = pk_fma(ew2, u6, acc[j][6]);
                    acc[j][7] = pk_fma(ew2, u7, acc[j][7]);
                    acc[j][8] = pk_fma(ew2, u8, acc[j][8]);
                    accd[j] += ew;
                }
            }
        }
    }

    if (!FINAL) {
        // combine the 4 px-group partners (lanes L^1, L^2) via 2-round
        // register reduce-scatter; each thread ends with 1 full pp row.
        const bool h1 = (L & 1);
        f32x2 r0[9], r1[9]; float rd0, rd1;
#pragma unroll
        for (int d = 0; d < 9; ++d) {
            f32x2 keep0 = h1 ? acc[2][d] : acc[0][d];
            f32x2 send0 = h1 ? acc[0][d] : acc[2][d];
            r0[d].x = keep0.x + __shfl_xor(send0.x, 1);
            r0[d].y = keep0.y + __shfl_xor(send0.y, 1);
            f32x2 keep1 = h1 ? acc[3][d] : acc[1][d];
            f32x2 send1 = h1 ? acc[1][d] : acc[3][d];
            r1[d].x = keep1.x + __shfl_xor(send1.x, 1);
            r1[d].y = keep1.y + __shfl_xor(send1.y, 1);
        }
        rd0 = (h1 ? accd[2] : accd[0]) + __shfl_xor(h1 ? accd[0] : accd[2], 1);
        rd1 = (h1 ? accd[3] : accd[1]) + __shfl_xor(h1 ? accd[1] : accd[3], 1);

        const bool h2 = (L & 2);
        f32x2 f0[9]; float fd;
#pragma unroll
        for (int d = 0; d < 9; ++d) {
            f32x2 keep = h2 ? r1[d] : r0[d];
            f32x2 send = h2 ? r0[d] : r1[d];
            f0[d].x = keep.x + __shfl_xor(send.x, 2);
            f0[d].y = keep.y + __shfl_xor(send.y, 2);
        }
        fd = (h2 ? rd1 : rd0) + __shfl_xor(h2 ? rd0 : rd1, 2);

        const int m_own = wv*64 + msub + 16*((int)((L&1)<<1) + ((L>>1)&1));
        float* dst = wout + ((size_t)(b*CHUNKS + chunk)*MM + m_own)*PROW;
        float4* dv = reinterpret_cast<float4*>(dst);
        dv[0] = make_float4(f0[0].x, f0[0].y, f0[1].x, f0[1].y);
        dv[1] = make_float4(f0[2].x, f0[2].y, f0[3].x, f0[3].y);
        dv[2] = make_float4(f0[4].x, f0[4].y, f0[5].x, f0[5].y);
        dv[3] = make_float4(f0[6].x, f0[6].y, f0[7].x, f0[7].y);
        dv[4] = make_float4(f0[8].x, f0[8].y, fd, 0.f);   // [18]=den
    }
}

// ---------------------------------------------------------------------------
// Sum the 512 per-chunk partials for each (b,m); produce new centers row
// (c, ||c||^2) and optionally centers_feat. block=(b,m), thread=chunk low 8b.
// ---------------------------------------------------------------------------
__global__ __launch_bounds__(256)
void reduce_finalize(const float* __restrict__ pp, float* __restrict__ cbuf,
                     float* __restrict__ cfout, int write_cf)
{
    const int b   = blockIdx.x >> 8;
    const int m   = blockIdx.x & 255;
    const int tid = threadIdx.x;
    const int lane = tid & 63, wv = tid >> 6;

    const float4* r0 = reinterpret_cast<const float4*>(
        pp + ((size_t)(b*CHUNKS + tid)*MM + m)*PROW);
    const float4* r1 = reinterpret_cast<const float4*>(
        pp + ((size_t)(b*CHUNKS + tid + 256)*MM + m)*PROW);
    float a[19];
    {
        float4 u0=r0[0], u1=r0[1], u2=r0[2], u3=r0[3], u4=r0[4];
        float4 w0=r1[0], w1=r1[1], w2=r1[2], w3=r1[3], w4=r1[4];
        a[0]=u0.x+w0.x;  a[1]=u0.y+w0.y;  a[2]=u0.z+w0.z;  a[3]=u0.w+w0.w;
        a[4]=u1.x+w1.x;  a[5]=u1.y+w1.y;  a[6]=u1.z+w1.z;  a[7]=u1.w+w1.w;
        a[8]=u2.x+w2.x;  a[9]=u2.y+w2.y;  a[10]=u2.z+w2.z; a[11]=u2.w+w2.w;
        a[12]=u3.x+w3.x; a[13]=u3.y+w3.y; a[14]=u3.z+w3.z; a[15]=u3.w+w3.w;
        a[16]=u4.x+w4.x; a[17]=u4.y+w4.y; a[18]=u4.z+w4.z;
    }
#pragma unroll
    for (int off = 32; off; off >>= 1) {
#pragma unroll
        for (int d = 0; d < 19; ++d) a[d] += __shfl_down(a[d], off);
    }

    __shared__ float red[4][20];
    if (lane == 0) {
#pragma unroll
        for (int d = 0; d < 19; ++d) red[wv][d] = a[d];
    }
    __syncthreads();
    if (tid == 0) {
        float s[19];
#pragma unroll
        for (int d = 0; d < 19; ++d)
            s[d] = red[0][d] + red[1][d] + red[2][d] + red[3][d];
        float den = s[18] + 1e-6f;
        float* row = cbuf + (b*MM + m)*CROW;
        float cn2 = 0.f;
#pragma unroll
        for (int d = 0; d < 18; ++d) {
            float cv = s[d] / den;
            row[d] = cv;
            cn2 = fmaf(cv, cv, cn2);
            if (write_cf && d < 16) cfout[((b*CC + d) << 8) + m] = cv;
        }
        row[18] = cn2;
        row[19] = 0.f;
    }
}

// ---------------------------------------------------------------------------
extern "C" void kernel_launch(void* const* d_in, const int* in_sizes, int n_in,
                              void* d_out, int out_size, void* d_ws, size_t ws_size,
                              hipStream_t stream)
{
    const float* feat = (const float*)d_in[0];
    float* dout = (float*)d_out;

    // d_ws layout: cbuf (128 KB) | ptbuf 21 MB | pp 42 MB
    float* cbuf  = (float*)d_ws;
    float* ptbuf = cbuf + 32768;
    float* pp    = ptbuf + (size_t)BB*NN*PROW;

    float* qout  = dout;                                // [B, N, M]
    float* cfout = dout + (size_t)BB*NN*MM;             // [B, C, M]

    build_pt<<<dim3(BB*256), dim3(256), 0, stream>>>(feat, ptbuf);
    init_centers<<<dim3(BB*MM), dim3(64), 0, stream>>>(feat, cbuf);

    for (int it = 0; it < 2; ++it) {
        ssn_iter<false><<<dim3(BB*CHUNKS), dim3(256), 0, stream>>>(ptbuf, cbuf, pp);
        reduce_finalize<<<dim3(BB*MM), dim3(256), 0, stream>>>(pp, cbuf, cfout, it == 1);
    }
    ssn_iter<true><<<dim3(BB*CHUNKS), dim3(256), 0, stream>>>(ptbuf, cbuf, qout);
}

// Round 11
// 350.042 us; speedup vs baseline: 1.8915x; 1.8915x over previous
//
#include <hip/hip_runtime.h>
#include <math.h>

// Problem constants (B,C,H,W fixed by the reference)
#define BB 4
#define CC 16
#define HH 256
#define WW 256
#define NN (HH*WW)        // 65536 pixels per batch
#define MM 256            // superpixels
#define CROW 20           // padded center row: c[0..17], [18]=||c||^2, [19]=pad
#define PROW 20           // pixel row: p[0..17], [18]=||p||^2, [19]=1.0
#define PIX 32            // pixels per sub-tile
#define TSUB 4            // sub-tiles per block (128 px/block)
#define PIXPERBLK (PIX*TSUB)
#define CHUNKS (NN/PIXPERBLK)   // 512 chunks per batch

typedef float f32x2 __attribute__((ext_vector_type(2)));

__device__ __forceinline__ f32x2 mk2(float a, float b) { f32x2 r; r.x = a; r.y = b; return r; }
// Packed fp32 FMA: lowers to v_pk_fma_f32 (VOP3P) — 2 lanes of f32 per instr.
__device__ __forceinline__ f32x2 pk_fma(f32x2 a, f32x2 b, f32x2 c) {
    return __builtin_elementwise_fma(a, b, c);
}

// ---------------------------------------------------------------------------
// Initial centers: 16x16 block means of features + analytic xy means + ||c||^2
// ---------------------------------------------------------------------------
__global__ void init_centers(const float* __restrict__ feat, float* __restrict__ cbuf)
{
    const int b    = blockIdx.x >> 8;
    const int m    = blockIdx.x & 255;
    const int lane = threadIdx.x;          // 0..63
    const int sy = m >> 4, sx = m & 15;

    float cvals[16];
#pragma unroll
    for (int d = 0; d < 16; ++d) {
        float v = 0.f;
#pragma unroll
        for (int k = 0; k < 4; ++k) {
            int q  = lane + (k << 6);            // 0..255 within 16x16 block
            int py = q >> 4, px = q & 15;
            int n  = (sy*16 + py)*WW + sx*16 + px;
            v += feat[((b*CC + d) << 16) + n];
        }
#pragma unroll
        for (int off = 32; off; off >>= 1) v += __shfl_down(v, off);
        cvals[d] = v * (1.f/256.f);
    }
    if (lane == 0) {
        float* row = cbuf + (b*MM + m)*CROW;
        float cn2 = 0.f;
#pragma unroll
        for (int d = 0; d < 16; ++d) { row[d] = cvals[d]; cn2 = fmaf(cvals[d], cvals[d], cn2); }
        float cx = (sx*16 + 7.5f) * (1.f/256.f);
        float cy = (sy*16 + 7.5f) * (1.f/256.f);
        row[16] = cx; row[17] = cy;
        cn2 = fmaf(cx, cx, cn2);
        cn2 = fmaf(cy, cy, cn2);
        row[18] = cn2;
        row[19] = 0.f;
    }
}

// ---------------------------------------------------------------------------
// Pre-transpose: pixel rows {p[0..17], ||p||^2, 1.0} into contiguous
// ptbuf[b][n][20] in d_ws.
// ---------------------------------------------------------------------------
__global__ void build_pt(const float* __restrict__ feat, float* __restrict__ ptbuf)
{
    const int b = blockIdx.x >> 8;
    const int n = ((blockIdx.x & 255) << 8) | threadIdx.x;
    float v[16];
#pragma unroll
    for (int d = 0; d < 16; ++d) v[d] = feat[((b*CC + d) << 16) + n];
    float x = (float)(n & 255) * (1.f/256.f);
    float y = (float)(n >> 8) * (1.f/256.f);
    float pn2 = 0.f;
#pragma unroll
    for (int d = 0; d < 16; ++d) pn2 = fmaf(v[d], v[d], pn2);
    pn2 = fmaf(x, x, pn2);
    pn2 = fmaf(y, y, pn2);
    float4* row = reinterpret_cast<float4*>(ptbuf + (size_t)(b*NN + n)*PROW);
    row[0] = make_float4(v[0],  v[1],  v[2],  v[3]);
    row[1] = make_float4(v[4],  v[5],  v[6],  v[7]);
    row[2] = make_float4(v[8],  v[9],  v[10], v[11]);
    row[3] = make_float4(v[12], v[13], v[14], v[15]);
    row[4] = make_float4(x, y, pn2, 1.0f);
}

// ---------------------------------------------------------------------------
// Non-final iteration kernel, KM=4 RECOMPUTE variant: lane L of wave wv
// handles 4 centers m = wv*64 + (L>>2) + 16j over 8 pixels px = (L&3) + 4k.
// Each LDS p-row read amortized over 4 dots (LDS pipe = measured bottleneck).
// NO e-array: phase 1 accumulates only the denominator partials s[k]; phase 2
// recomputes dot+exp (VALU is far under the LDS roof). This + waves_per_eu(2,2)
// kills the round-10 spill (VGPR capped at 128 -> 600 MB scratch traffic).
// ---------------------------------------------------------------------------
__global__ __launch_bounds__(256)
__attribute__((amdgpu_waves_per_eu(2, 2)))
void ssn_nf(const float* __restrict__ ptbuf, const float* __restrict__ cbuf,
            float* __restrict__ pp)
{
    __shared__ __align__(16) float pls[PIXPERBLK*PROW];   // 10240 B
    __shared__ float ssum_s[TSUB][4][PIX];                //  2048 B
    __shared__ float w_s[TSUB][PIX];                      //   512 B

    const int tid    = threadIdx.x;
    const int b      = blockIdx.x >> 9;
    const int chunk  = blockIdx.x & (CHUNKS-1);
    const int n_base = chunk * PIXPERBLK;
    const int L      = tid & 63;
    const int wv     = tid >> 6;
    const int g      = L & 3;              // px group: px = g + 4k
    const int msub   = L >> 2;             // 0..15
    const int mbase  = wv*64 + msub;       // m_j = mbase + 16*j

    // ---- stage 128 rows x 80 B, fully coalesced & contiguous ----
    {
        const float4* src = reinterpret_cast<const float4*>(
            ptbuf + (size_t)(b*NN + n_base)*PROW);
#pragma unroll
        for (int k = 0; k < 3; ++k) {
            int f = tid + (k << 8);
            if (f < PIXPERBLK*PROW/4)
                reinterpret_cast<float4*>(pls)[f] = src[f];
        }
    }

    // center registers for 4 m's, packed pairs
    f32x2 cp[4][9]; float cn2[4];
#pragma unroll
    for (int j = 0; j < 4; ++j) {
        const float4* cv = reinterpret_cast<const float4*>(
            cbuf + (b*MM + mbase + 16*j)*CROW);
        float4 a0 = cv[0], a1 = cv[1], a2 = cv[2], a3 = cv[3], a4 = cv[4];
        cp[j][0]=mk2(a0.x,a0.y); cp[j][1]=mk2(a0.z,a0.w);
        cp[j][2]=mk2(a1.x,a1.y); cp[j][3]=mk2(a1.z,a1.w);
        cp[j][4]=mk2(a2.x,a2.y); cp[j][5]=mk2(a2.z,a2.w);
        cp[j][6]=mk2(a3.x,a3.y); cp[j][7]=mk2(a3.z,a3.w);
        cp[j][8]=mk2(a4.x,a4.y); cn2[j]=a4.z;
    }

    f32x2 acc[4][9]; float accd[4];
#pragma unroll
    for (int j = 0; j < 4; ++j) {
#pragma unroll
        for (int d = 0; d < 9; ++d) acc[j][d] = mk2(0.f, 0.f);
        accd[j] = 0.f;
    }

    __syncthreads();   // pls ready

    for (int t = 0; t < TSUB; ++t) {
        // ---- phase 1: denominator partials only (e consumed immediately) ----
        float s[8];
#pragma unroll
        for (int k = 0; k < 8; ++k) {
            const int row = t*PIX + g + 4*k;
            const float4* pv = reinterpret_cast<const float4*>(&pls[row*PROW]);
            float4 q0 = pv[0], q1 = pv[1], q2 = pv[2], q3 = pv[3], q4 = pv[4];
            f32x2 u0=mk2(q0.x,q0.y), u1=mk2(q0.z,q0.w), u2=mk2(q1.x,q1.y),
                  u3=mk2(q1.z,q1.w), u4=mk2(q2.x,q2.y), u5=mk2(q2.z,q2.w),
                  u6=mk2(q3.x,q3.y), u7=mk2(q3.z,q3.w), u8=mk2(q4.x,q4.y);
            f32x2 d0=mk2(0.f,0.f), d1=mk2(0.f,0.f), d2v=mk2(0.f,0.f), d3=mk2(0.f,0.f);
            d0 = pk_fma(u0, cp[0][0], d0); d1 = pk_fma(u0, cp[1][0], d1);
            d2v= pk_fma(u0, cp[2][0], d2v);d3 = pk_fma(u0, cp[3][0], d3);
            d0 = pk_fma(u1, cp[0][1], d0); d1 = pk_fma(u1, cp[1][1], d1);
            d2v= pk_fma(u1, cp[2][1], d2v);d3 = pk_fma(u1, cp[3][1], d3);
            d0 = pk_fma(u2, cp[0][2], d0); d1 = pk_fma(u2, cp[1][2], d1);
            d2v= pk_fma(u2, cp[2][2], d2v);d3 = pk_fma(u2, cp[3][2], d3);
            d0 = pk_fma(u3, cp[0][3], d0); d1 = pk_fma(u3, cp[1][3], d1);
            d2v= pk_fma(u3, cp[2][3], d2v);d3 = pk_fma(u3, cp[3][3], d3);
            d0 = pk_fma(u4, cp[0][4], d0); d1 = pk_fma(u4, cp[1][4], d1);
            d2v= pk_fma(u4, cp[2][4], d2v);d3 = pk_fma(u4, cp[3][4], d3);
            d0 = pk_fma(u5, cp[0][5], d0); d1 = pk_fma(u5, cp[1][5], d1);
            d2v= pk_fma(u5, cp[2][5], d2v);d3 = pk_fma(u5, cp[3][5], d3);
            d0 = pk_fma(u6, cp[0][6], d0); d1 = pk_fma(u6, cp[1][6], d1);
            d2v= pk_fma(u6, cp[2][6], d2v);d3 = pk_fma(u6, cp[3][6], d3);
            d0 = pk_fma(u7, cp[0][7], d0); d1 = pk_fma(u7, cp[1][7], d1);
            d2v= pk_fma(u7, cp[2][7], d2v);d3 = pk_fma(u7, cp[3][7], d3);
            d0 = pk_fma(u8, cp[0][8], d0); d1 = pk_fma(u8, cp[1][8], d1);
            d2v= pk_fma(u8, cp[2][8], d2v);d3 = pk_fma(u8, cp[3][8], d3);
            float s0 = fmaf(-2.f, d0.x + d0.y, q4.z + cn2[0]);
            float s1 = fmaf(-2.f, d1.x + d1.y, q4.z + cn2[1]);
            float s2 = fmaf(-2.f, d2v.x + d2v.y, q4.z + cn2[2]);
            float s3 = fmaf(-2.f, d3.x + d3.y, q4.z + cn2[3]);
            float e0 = __expf(-__builtin_amdgcn_sqrtf(fmaxf(s0, 1e-12f)));
            float e1 = __expf(-__builtin_amdgcn_sqrtf(fmaxf(s1, 1e-12f)));
            float e2 = __expf(-__builtin_amdgcn_sqrtf(fmaxf(s2, 1e-12f)));
            float e3 = __expf(-__builtin_amdgcn_sqrtf(fmaxf(s3, 1e-12f)));
            s[k] = (e0 + e1) + (e2 + e3);
        }

        // ---- intra-wave softmax partial: 16-lane reduce-scatter over 8 px ----
#define RS_ROUND(MASK, H) { const bool hi = (L & (MASK)); \
        _Pragma("unroll") \
        for (int k = 0; k < (H); ++k) { \
            float a = s[k], bq = s[k+(H)]; \
            float recv = __shfl_xor(hi ? a : bq, (MASK)); \
            s[k] = (hi ? bq : a) + recv; } }
        RS_ROUND(4, 4)
        RS_ROUND(8, 2)
        RS_ROUND(16, 1)
#undef RS_ROUND
        s[0] += __shfl_xor(s[0], 32);
        {
            const int kown = (((L>>2)&1)<<2) | (((L>>3)&1)<<1) | ((L>>4)&1);
            if (L < 32) ssum_s[t][wv][g + 4*kown] = s[0];
        }
        __syncthreads();
        if (tid < 32) {
            w_s[t][tid] = 1.0f / (ssum_s[t][0][tid] + ssum_s[t][1][tid]
                                + ssum_s[t][2][tid] + ssum_s[t][3][tid]);
        }
        __syncthreads();

        // ---- phase 2: re-read row, RECOMPUTE dot+exp, accumulate ----
#pragma unroll
        for (int k = 0; k < 8; ++k) {
            const int row = t*PIX + g + 4*k;
            const float4* pv = reinterpret_cast<const float4*>(&pls[row*PROW]);
            float4 q0 = pv[0], q1 = pv[1], q2 = pv[2], q3 = pv[3], q4 = pv[4];
            f32x2 u0=mk2(q0.x,q0.y), u1=mk2(q0.z,q0.w), u2=mk2(q1.x,q1.y),
                  u3=mk2(q1.z,q1.w), u4=mk2(q2.x,q2.y), u5=mk2(q2.z,q2.w),
                  u6=mk2(q3.x,q3.y), u7=mk2(q3.z,q3.w), u8=mk2(q4.x,q4.y);
            f32x2 d0=mk2(0.f,0.f), d1=mk2(0.f,0.f), d2v=mk2(0.f,0.f), d3=mk2(0.f,0.f);
            d0 = pk_fma(u0, cp[0][0], d0); d1 = pk_fma(u0, cp[1][0], d1);
            d2v= pk_fma(u0, cp[2][0], d2v);d3 = pk_fma(u0, cp[3][0], d3);
            d0 = pk_fma(u1, cp[0][1], d0); d1 = pk_fma(u1, cp[1][1], d1);
            d2v= pk_fma(u1, cp[2][1], d2v);d3 = pk_fma(u1, cp[3][1], d3);
            d0 = pk_fma(u2, cp[0][2], d0); d1 = pk_fma(u2, cp[1][2], d1);
            d2v= pk_fma(u2, cp[2][2], d2v);d3 = pk_fma(u2, cp[3][2], d3);
            d0 = pk_fma(u3, cp[0][3], d0); d1 = pk_fma(u3, cp[1][3], d1);
            d2v= pk_fma(u3, cp[2][3], d2v);d3 = pk_fma(u3, cp[3][3], d3);
            d0 = pk_fma(u4, cp[0][4], d0); d1 = pk_fma(u4, cp[1][4], d1);
            d2v= pk_fma(u4, cp[2][4], d2v);d3 = pk_fma(u4, cp[3][4], d3);
            d0 = pk_fma(u5, cp[0][5], d0); d1 = pk_fma(u5, cp[1][5], d1);
            d2v= pk_fma(u5, cp[2][5], d2v);d3 = pk_fma(u5, cp[3][5], d3);
            d0 = pk_fma(u6, cp[0][6], d0); d1 = pk_fma(u6, cp[1][6], d1);
            d2v= pk_fma(u6, cp[2][6], d2v);d3 = pk_fma(u6, cp[3][6], d3);
            d0 = pk_fma(u7, cp[0][7], d0); d1 = pk_fma(u7, cp[1][7], d1);
            d2v= pk_fma(u7, cp[2][7], d2v);d3 = pk_fma(u7, cp[3][7], d3);
            d0 = pk_fma(u8, cp[0][8], d0); d1 = pk_fma(u8, cp[1][8], d1);
            d2v= pk_fma(u8, cp[2][8], d2v);d3 = pk_fma(u8, cp[3][8], d3);
            float s0 = fmaf(-2.f, d0.x + d0.y, q4.z + cn2[0]);
            float s1 = fmaf(-2.f, d1.x + d1.y, q4.z + cn2[1]);
            float s2 = fmaf(-2.f, d2v.x + d2v.y, q4.z + cn2[2]);
            float s3 = fmaf(-2.f, d3.x + d3.y, q4.z + cn2[3]);
            float w = w_s[t][g + 4*k];
            float e0 = __expf(-__builtin_amdgcn_sqrtf(fmaxf(s0, 1e-12f))) * w;
            float e1 = __expf(-__builtin_amdgcn_sqrtf(fmaxf(s1, 1e-12f))) * w;
            float e2 = __expf(-__builtin_amdgcn_sqrtf(fmaxf(s2, 1e-12f))) * w;
            float e3 = __expf(-__builtin_amdgcn_sqrtf(fmaxf(s3, 1e-12f))) * w;
            f32x2 ew0 = mk2(e0,e0), ew1 = mk2(e1,e1), ew2 = mk2(e2,e2), ew3 = mk2(e3,e3);
            acc[0][0]=pk_fma(ew0,u0,acc[0][0]); acc[1][0]=pk_fma(ew1,u0,acc[1][0]);
            acc[2][0]=pk_fma(ew2,u0,acc[2][0]); acc[3][0]=pk_fma(ew3,u0,acc[3][0]);
            acc[0][1]=pk_fma(ew0,u1,acc[0][1]); acc[1][1]=pk_fma(ew1,u1,acc[1][1]);
            acc[2][1]=pk_fma(ew2,u1,acc[2][1]); acc[3][1]=pk_fma(ew3,u1,acc[3][1]);
            acc[0][2]=pk_fma(ew0,u2,acc[0][2]); acc[1][2]=pk_fma(ew1,u2,acc[1][2]);
            acc[2][2]=pk_fma(ew2,u2,acc[2][2]); acc[3][2]=pk_fma(ew3,u2,acc[3][2]);
            acc[0][3]=pk_fma(ew0,u3,acc[0][3]); acc[1][3]=pk_fma(ew1,u3,acc[1][3]);
            acc[2][3]=pk_fma(ew2,u3,acc[2][3]); acc[3][3]=pk_fma(ew3,u3,acc[3][3]);
            acc[0][4]=pk_fma(ew0,u4,acc[0][4]); acc[1][4]=pk_fma(ew1,u4,acc[1][4]);
            acc[2][4]=pk_fma(ew2,u4,acc[2][4]); acc[3][4]=pk_fma(ew3,u4,acc[3][4]);
            acc[0][5]=pk_fma(ew0,u5,acc[0][5]); acc[1][5]=pk_fma(ew1,u5,acc[1][5]);
            acc[2][5]=pk_fma(ew2,u5,acc[2][5]); acc[3][5]=pk_fma(ew3,u5,acc[3][5]);
            acc[0][6]=pk_fma(ew0,u6,acc[0][6]); acc[1][6]=pk_fma(ew1,u6,acc[1][6]);
            acc[2][6]=pk_fma(ew2,u6,acc[2][6]); acc[3][6]=pk_fma(ew3,u6,acc[3][6]);
            acc[0][7]=pk_fma(ew0,u7,acc[0][7]); acc[1][7]=pk_fma(ew1,u7,acc[1][7]);
            acc[2][7]=pk_fma(ew2,u7,acc[2][7]); acc[3][7]=pk_fma(ew3,u7,acc[3][7]);
            acc[0][8]=pk_fma(ew0,u8,acc[0][8]); acc[1][8]=pk_fma(ew1,u8,acc[1][8]);
            acc[2][8]=pk_fma(ew2,u8,acc[2][8]); acc[3][8]=pk_fma(ew3,u8,acc[3][8]);
            accd[0]+=e0; accd[1]+=e1; accd[2]+=e2; accd[3]+=e3;
        }
    }

    // combine the 4 px-group partners (lanes L^1, L^2) via 2-round register
    // reduce-scatter; each thread ends with 1 full pp row. (proven in r10)
    const bool h1 = (L & 1);
    f32x2 r0[9], r1[9]; float rd0, rd1;
#pragma unroll
    for (int d = 0; d < 9; ++d) {
        f32x2 keep0 = h1 ? acc[2][d] : acc[0][d];
        f32x2 send0 = h1 ? acc[0][d] : acc[2][d];
        r0[d].x = keep0.x + __shfl_xor(send0.x, 1);
        r0[d].y = keep0.y + __shfl_xor(send0.y, 1);
        f32x2 keep1 = h1 ? acc[3][d] : acc[1][d];
        f32x2 send1 = h1 ? acc[1][d] : acc[3][d];
        r1[d].x = keep1.x + __shfl_xor(send1.x, 1);
        r1[d].y = keep1.y + __shfl_xor(send1.y, 1);
    }
    rd0 = (h1 ? accd[2] : accd[0]) + __shfl_xor(h1 ? accd[0] : accd[2], 1);
    rd1 = (h1 ? accd[3] : accd[1]) + __shfl_xor(h1 ? accd[1] : accd[3], 1);

    const bool h2 = (L & 2);
    f32x2 f0[9]; float fd;
#pragma unroll
    for (int d = 0; d < 9; ++d) {
        f32x2 keep = h2 ? r1[d] : r0[d];
        f32x2 send = h2 ? r0[d] : r1[d];
        f0[d].x = keep.x + __shfl_xor(send.x, 2);
        f0[d].y = keep.y + __shfl_xor(send.y, 2);
    }
    fd = (h2 ? rd1 : rd0) + __shfl_xor(h2 ? rd0 : rd1, 2);

    const int m_own = wv*64 + msub + 16*((int)((L&1)<<1) + ((L>>1)&1));
    float* dst = pp + ((size_t)(b*CHUNKS + chunk)*MM + m_own)*PROW;
    float4* dv = reinterpret_cast<float4*>(dst);
    dv[0] = make_float4(f0[0].x, f0[0].y, f0[1].x, f0[1].y);
    dv[1] = make_float4(f0[2].x, f0[2].y, f0[3].x, f0[3].y);
    dv[2] = make_float4(f0[4].x, f0[4].y, f0[5].x, f0[5].y);
    dv[3] = make_float4(f0[6].x, f0[6].y, f0[7].x, f0[7].y);
    dv[4] = make_float4(f0[8].x, f0[8].y, fd, 0.f);   // [18]=den
}

// ---------------------------------------------------------------------------
// Final iteration kernel: proven round-9 KM=2 path (coalesced Q store).
// ---------------------------------------------------------------------------
__global__ __launch_bounds__(256, 3)
void ssn_fin(const float* __restrict__ ptbuf, const float* __restrict__ cbuf,
             float* __restrict__ qout)
{
    __shared__ __align__(16) float pls[PIXPERBLK*PROW];   // 10240 B
    __shared__ float ssum_s[TSUB][4][16];
    __shared__ float w_s[TSUB][PIX];

    const int tid    = threadIdx.x;
    const int b      = blockIdx.x >> 9;
    const int chunk  = blockIdx.x & (CHUNKS-1);
    const int n_base = chunk * PIXPERBLK;
    const int lane   = tid & 63;
    const int wv     = tid >> 6;
    const int mlo    = tid & 127;          // m0 = mlo, m1 = mlo + 128
    const int pxbase = (tid >> 7) << 4;    // 0 or 16

    {
        const float4* src = reinterpret_cast<const float4*>(
            ptbuf + (size_t)(b*NN + n_base)*PROW);
#pragma unroll
        for (int k = 0; k < 3; ++k) {
            int f = tid + (k << 8);
            if (f < PIXPERBLK*PROW/4)
                reinterpret_cast<float4*>(pls)[f] = src[f];
        }
    }

    f32x2 cp0[9], cp1[9]; float cn20, cn21;
    {
        const float4* cv = reinterpret_cast<const float4*>(cbuf + (b*MM + mlo)*CROW);
        float4 a0 = cv[0], a1 = cv[1], a2 = cv[2], a3 = cv[3], a4 = cv[4];
        cp0[0]=mk2(a0.x,a0.y); cp0[1]=mk2(a0.z,a0.w);
        cp0[2]=mk2(a1.x,a1.y); cp0[3]=mk2(a1.z,a1.w);
        cp0[4]=mk2(a2.x,a2.y); cp0[5]=mk2(a2.z,a2.w);
        cp0[6]=mk2(a3.x,a3.y); cp0[7]=mk2(a3.z,a3.w);
        cp0[8]=mk2(a4.x,a4.y); cn20=a4.z;
    }
    {
        const float4* cv = reinterpret_cast<const float4*>(cbuf + (b*MM + mlo + 128)*CROW);
        float4 a0 = cv[0], a1 = cv[1], a2 = cv[2], a3 = cv[3], a4 = cv[4];
        cp1[0]=mk2(a0.x,a0.y); cp1[1]=mk2(a0.z,a0.w);
        cp1[2]=mk2(a1.x,a1.y); cp1[3]=mk2(a1.z,a1.w);
        cp1[4]=mk2(a2.x,a2.y); cp1[5]=mk2(a2.z,a2.w);
        cp1[6]=mk2(a3.x,a3.y); cp1[7]=mk2(a3.z,a3.w);
        cp1[8]=mk2(a4.x,a4.y); cn21=a4.z;
    }

    const int pxo4 = ((lane&1)<<3) | ((lane&2)<<1) | ((lane&4)>>1) | ((lane&8)>>3);

    __syncthreads();   // pls ready

    for (int t = 0; t < TSUB; ++t) {
        float e0[16], e1[16];
#pragma unroll
        for (int k = 0; k < 16; ++k) {
            const float4* pv = reinterpret_cast<const float4*>(
                &pls[(t*PIX + pxbase + k)*PROW]);
            float4 q0 = pv[0], q1 = pv[1], q2 = pv[2], q3 = pv[3], q4 = pv[4];
            f32x2 u0=mk2(q0.x,q0.y), u1=mk2(q0.z,q0.w), u2=mk2(q1.x,q1.y),
                  u3=mk2(q1.z,q1.w), u4=mk2(q2.x,q2.y), u5=mk2(q2.z,q2.w),
                  u6=mk2(q3.x,q3.y), u7=mk2(q3.z,q3.w), u8=mk2(q4.x,q4.y);
            f32x2 d0 = mk2(0.f,0.f), d1 = mk2(0.f,0.f);
            d0 = pk_fma(u0, cp0[0], d0);  d1 = pk_fma(u0, cp1[0], d1);
            d0 = pk_fma(u1, cp0[1], d0);  d1 = pk_fma(u1, cp1[1], d1);
            d0 = pk_fma(u2, cp0[2], d0);  d1 = pk_fma(u2, cp1[2], d1);
            d0 = pk_fma(u3, cp0[3], d0);  d1 = pk_fma(u3, cp1[3], d1);
            d0 = pk_fma(u4, cp0[4], d0);  d1 = pk_fma(u4, cp1[4], d1);
            d0 = pk_fma(u5, cp0[5], d0);  d1 = pk_fma(u5, cp1[5], d1);
            d0 = pk_fma(u6, cp0[6], d0);  d1 = pk_fma(u6, cp1[6], d1);
            d0 = pk_fma(u7, cp0[7], d0);  d1 = pk_fma(u7, cp1[7], d1);
            d0 = pk_fma(u8, cp0[8], d0);  d1 = pk_fma(u8, cp1[8], d1);
            float d20 = fmaf(-2.f, d0.x + d0.y, q4.z + cn20);
            float d21 = fmaf(-2.f, d1.x + d1.y, q4.z + cn21);
            e0[k] = __expf(-__builtin_amdgcn_sqrtf(fmaxf(d20, 1e-12f)));
            e1[k] = __expf(-__builtin_amdgcn_sqrtf(fmaxf(d21, 1e-12f)));
        }

        float s[8];
        {
            const bool hi = (lane & 1);
#pragma unroll
            for (int k = 0; k < 8; ++k) {
                float a  = e0[k]   + e1[k];
                float bq = e0[k+8] + e1[k+8];
                float recv = __shfl_xor(hi ? a : bq, 1);
                s[k] = (hi ? bq : a) + recv;
            }
        }
#define RS_ROUND(MASK, H) { const bool hi = (lane & (MASK)); \
        _Pragma("unroll") \
        for (int k = 0; k < (H); ++k) { \
            float a = s[k], bq = s[k+(H)]; \
            float recv = __shfl_xor(hi ? a : bq, (MASK)); \
            s[k] = (hi ? bq : a) + recv; } }
        RS_ROUND(2, 4)
        RS_ROUND(4, 2)
        RS_ROUND(8, 1)
#undef RS_ROUND
        s[0] += __shfl_xor(s[0], 16);
        s[0] += __shfl_xor(s[0], 32);
        if (lane < 16) ssum_s[t][wv][pxo4] = s[0];
        __syncthreads();
        if (tid < 32) {
            int h = tid >> 4, p4 = tid & 15;
            w_s[t][tid] = 1.0f / (ssum_s[t][2*h][p4] + ssum_s[t][2*h+1][p4]);
        }
        __syncthreads();

#pragma unroll
        for (int k = 0; k < 16; ++k) {
            float w = w_s[t][pxbase + k];
            size_t rowoff = ((size_t)(b*NN + n_base + t*PIX + pxbase + k) << 8);
            qout[rowoff + mlo]       = e0[k] * w;
            qout[rowoff + mlo + 128] = e1[k] * w;
        }
    }
}

// ---------------------------------------------------------------------------
// Sum the 512 per-chunk partials for each (b,m); produce new centers row
// (c, ||c||^2) and optionally centers_feat. block=(b,m), thread=chunk low 8b.
// ---------------------------------------------------------------------------
__global__ __launch_bounds__(256)
void reduce_finalize(const float* __restrict__ pp, float* __restrict__ cbuf,
                     float* __restrict__ cfout, int write_cf)
{
    const int b   = blockIdx.x >> 8;
    const int m   = blockIdx.x & 255;
    const int tid = threadIdx.x;
    const int lane = tid & 63, wv = tid >> 6;

    const float4* r0 = reinterpret_cast<const float4*>(
        pp + ((size_t)(b*CHUNKS + tid)*MM + m)*PROW);
    const float4* r1 = reinterpret_cast<const float4*>(
        pp + ((size_t)(b*CHUNKS + tid + 256)*MM + m)*PROW);
    float a[19];
    {
        float4 u0=r0[0], u1=r0[1], u2=r0[2], u3=r0[3], u4=r0[4];
        float4 w0=r1[0], w1=r1[1], w2=r1[2], w3=r1[3], w4=r1[4];
        a[0]=u0.x+w0.x;  a[1]=u0.y+w0.y;  a[2]=u0.z+w0.z;  a[3]=u0.w+w0.w;
        a[4]=u1.x+w1.x;  a[5]=u1.y+w1.y;  a[6]=u1.z+w1.z;  a[7]=u1.w+w1.w;
        a[8]=u2.x+w2.x;  a[9]=u2.y+w2.y;  a[10]=u2.z+w2.z; a[11]=u2.w+w2.w;
        a[12]=u3.x+w3.x; a[13]=u3.y+w3.y; a[14]=u3.z+w3.z; a[15]=u3.w+w3.w;
        a[16]=u4.x+w4.x; a[17]=u4.y+w4.y; a[18]=u4.z+w4.z;
    }
#pragma unroll
    for (int off = 32; off; off >>= 1) {
#pragma unroll
        for (int d = 0; d < 19; ++d) a[d] += __shfl_down(a[d], off);
    }

    __shared__ float red[4][20];
    if (lane == 0) {
#pragma unroll
        for (int d = 0; d < 19; ++d) red[wv][d] = a[d];
    }
    __syncthreads();
    if (tid == 0) {
        float s[19];
#pragma unroll
        for (int d = 0; d < 19; ++d)
            s[d] = red[0][d] + red[1][d] + red[2][d] + red[3][d];
        float den = s[18] + 1e-6f;
        float* row = cbuf + (b*MM + m)*CROW;
        float cn2 = 0.f;
#pragma unroll
        for (int d = 0; d < 18; ++d) {
            float cv = s[d] / den;
            row[d] = cv;
            cn2 = fmaf(cv, cv, cn2);
            if (write_cf && d < 16) cfout[((b*CC + d) << 8) + m] = cv;
        }
        row[18] = cn2;
        row[19] = 0.f;
    }
}

// ---------------------------------------------------------------------------
extern "C" void kernel_launch(void* const* d_in, const int* in_sizes, int n_in,
                              void* d_out, int out_size, void* d_ws, size_t ws_size,
                              hipStream_t stream)
{
    const float* feat = (const float*)d_in[0];
    float* dout = (float*)d_out;

    // d_ws layout: cbuf (128 KB) | ptbuf 21 MB | pp 42 MB
    float* cbuf  = (float*)d_ws;
    float* ptbuf = cbuf + 32768;
    float* pp    = ptbuf + (size_t)BB*NN*PROW;

    float* qout  = dout;                                // [B, N, M]
    float* cfout = dout + (size_t)BB*NN*MM;             // [B, C, M]

    build_pt<<<dim3(BB*256), dim3(256), 0, stream>>>(feat, ptbuf);
    init_centers<<<dim3(BB*MM), dim3(64), 0, stream>>>(feat, cbuf);

    for (int it = 0; it < 2; ++it) {
        ssn_nf<<<dim3(BB*CHUNKS), dim3(256), 0, stream>>>(ptbuf, cbuf, pp);
        reduce_finalize<<<dim3(BB*MM), dim3(256), 0, stream>>>(pp, cbuf, cfout, it == 1);
    }
    ssn_fin<<<dim3(BB*CHUNKS), dim3(256), 0, stream>>>(ptbuf, cbuf, qout);
}

// Round 12
// 275.090 us; speedup vs baseline: 2.4068x; 1.2725x over previous
//
#include <hip/hip_runtime.h>
#include <math.h>

// Problem constants (B,C,H,W fixed by the reference)
#define BB 4
#define CC 16
#define HH 256
#define WW 256
#define NN (HH*WW)        // 65536 pixels per batch
#define MM 256            // superpixels
#define CROW 20           // padded center row: c[0..17], [18]=||c||^2, [19]=pad
#define PROW 20           // pixel row: p[0..17], [18]=||p||^2, [19]=1.0
#define PIX 32            // pixels per sub-tile
#define TSUB 4            // sub-tiles per block (128 px/block)
#define PIXPERBLK (PIX*TSUB)
#define CHUNKS (NN/PIXPERBLK)   // 512 chunks per batch

typedef float f32x2 __attribute__((ext_vector_type(2)));

__device__ __forceinline__ f32x2 mk2(float a, float b) { f32x2 r; r.x = a; r.y = b; return r; }
// Packed fp32 FMA: lowers to v_pk_fma_f32 (VOP3P) — 2 lanes of f32 per instr.
__device__ __forceinline__ f32x2 pk_fma(f32x2 a, f32x2 b, f32x2 c) {
    return __builtin_elementwise_fma(a, b, c);
}

// ---------------------------------------------------------------------------
// Initial centers: 16x16 block means of features + analytic xy means + ||c||^2
// ---------------------------------------------------------------------------
__global__ void init_centers(const float* __restrict__ feat, float* __restrict__ cbuf)
{
    const int b    = blockIdx.x >> 8;
    const int m    = blockIdx.x & 255;
    const int lane = threadIdx.x;          // 0..63
    const int sy = m >> 4, sx = m & 15;

    float cvals[16];
#pragma unroll
    for (int d = 0; d < 16; ++d) {
        float v = 0.f;
#pragma unroll
        for (int k = 0; k < 4; ++k) {
            int q  = lane + (k << 6);            // 0..255 within 16x16 block
            int py = q >> 4, px = q & 15;
            int n  = (sy*16 + py)*WW + sx*16 + px;
            v += feat[((b*CC + d) << 16) + n];
        }
#pragma unroll
        for (int off = 32; off; off >>= 1) v += __shfl_down(v, off);
        cvals[d] = v * (1.f/256.f);
    }
    if (lane == 0) {
        float* row = cbuf + (b*MM + m)*CROW;
        float cn2 = 0.f;
#pragma unroll
        for (int d = 0; d < 16; ++d) { row[d] = cvals[d]; cn2 = fmaf(cvals[d], cvals[d], cn2); }
        float cx = (sx*16 + 7.5f) * (1.f/256.f);
        float cy = (sy*16 + 7.5f) * (1.f/256.f);
        row[16] = cx; row[17] = cy;
        cn2 = fmaf(cx, cx, cn2);
        cn2 = fmaf(cy, cy, cn2);
        row[18] = cn2;
        row[19] = 0.f;
    }
}

// ---------------------------------------------------------------------------
// Pre-transpose: pixel rows {p[0..17], ||p||^2, 1.0} into contiguous
// ptbuf[b][n][20] in d_ws.
// ---------------------------------------------------------------------------
__global__ void build_pt(const float* __restrict__ feat, float* __restrict__ ptbuf)
{
    const int b = blockIdx.x >> 8;
    const int n = ((blockIdx.x & 255) << 8) | threadIdx.x;
    float v[16];
#pragma unroll
    for (int d = 0; d < 16; ++d) v[d] = feat[((b*CC + d) << 16) + n];
    float x = (float)(n & 255) * (1.f/256.f);
    float y = (float)(n >> 8) * (1.f/256.f);
    float pn2 = 0.f;
#pragma unroll
    for (int d = 0; d < 16; ++d) pn2 = fmaf(v[d], v[d], pn2);
    pn2 = fmaf(x, x, pn2);
    pn2 = fmaf(y, y, pn2);
    float4* row = reinterpret_cast<float4*>(ptbuf + (size_t)(b*NN + n)*PROW);
    row[0] = make_float4(v[0],  v[1],  v[2],  v[3]);
    row[1] = make_float4(v[4],  v[5],  v[6],  v[7]);
    row[2] = make_float4(v[8],  v[9],  v[10], v[11]);
    row[3] = make_float4(v[12], v[13], v[14], v[15]);
    row[4] = make_float4(x, y, pn2, 1.0f);
}

// ---------------------------------------------------------------------------
// Non-final iteration kernel: PROVEN round-9 KM=2 path (83 us/dispatch).
// thread = (m-pair, px-half); centers + e in registers; p rows via LDS
// broadcast; partials combined across px-half partners via LDS xfer.
// ---------------------------------------------------------------------------
__global__ __launch_bounds__(256, 3)
void ssn_nf(const float* __restrict__ ptbuf, const float* __restrict__ cbuf,
            float* __restrict__ pp)
{
    __shared__ __align__(16) float pls[PIXPERBLK*PROW];   // 10240 B
    __shared__ float ssum_s[TSUB][4][16];                 //  1024 B
    __shared__ float w_s[TSUB][PIX];                      //   512 B
    __shared__ float xfer[128*41];                        // 20992 B

    const int tid    = threadIdx.x;
    const int b      = blockIdx.x >> 9;
    const int chunk  = blockIdx.x & (CHUNKS-1);
    const int n_base = chunk * PIXPERBLK;
    const int lane   = tid & 63;
    const int wv     = tid >> 6;
    const int mlo    = tid & 127;          // m0 = mlo, m1 = mlo + 128
    const int pxbase = (tid >> 7) << 4;    // 0 or 16

    {
        const float4* src = reinterpret_cast<const float4*>(
            ptbuf + (size_t)(b*NN + n_base)*PROW);
#pragma unroll
        for (int k = 0; k < 3; ++k) {
            int f = tid + (k << 8);
            if (f < PIXPERBLK*PROW/4)
                reinterpret_cast<float4*>(pls)[f] = src[f];
        }
    }

    f32x2 cp0[9], cp1[9]; float cn20, cn21;
    {
        const float4* cv = reinterpret_cast<const float4*>(cbuf + (b*MM + mlo)*CROW);
        float4 a0 = cv[0], a1 = cv[1], a2 = cv[2], a3 = cv[3], a4 = cv[4];
        cp0[0]=mk2(a0.x,a0.y); cp0[1]=mk2(a0.z,a0.w);
        cp0[2]=mk2(a1.x,a1.y); cp0[3]=mk2(a1.z,a1.w);
        cp0[4]=mk2(a2.x,a2.y); cp0[5]=mk2(a2.z,a2.w);
        cp0[6]=mk2(a3.x,a3.y); cp0[7]=mk2(a3.z,a3.w);
        cp0[8]=mk2(a4.x,a4.y); cn20=a4.z;
    }
    {
        const float4* cv = reinterpret_cast<const float4*>(cbuf + (b*MM + mlo + 128)*CROW);
        float4 a0 = cv[0], a1 = cv[1], a2 = cv[2], a3 = cv[3], a4 = cv[4];
        cp1[0]=mk2(a0.x,a0.y); cp1[1]=mk2(a0.z,a0.w);
        cp1[2]=mk2(a1.x,a1.y); cp1[3]=mk2(a1.z,a1.w);
        cp1[4]=mk2(a2.x,a2.y); cp1[5]=mk2(a2.z,a2.w);
        cp1[6]=mk2(a3.x,a3.y); cp1[7]=mk2(a3.z,a3.w);
        cp1[8]=mk2(a4.x,a4.y); cn21=a4.z;
    }

    f32x2 acc0[10], acc1[10];
#pragma unroll
    for (int k = 0; k < 10; ++k) { acc0[k] = mk2(0.f,0.f); acc1[k] = mk2(0.f,0.f); }

    const int pxo4 = ((lane&1)<<3) | ((lane&2)<<1) | ((lane&4)>>1) | ((lane&8)>>3);

    __syncthreads();   // pls ready

    for (int t = 0; t < TSUB; ++t) {
        float e0[16], e1[16];
#pragma unroll
        for (int k = 0; k < 16; ++k) {
            const float4* pv = reinterpret_cast<const float4*>(
                &pls[(t*PIX + pxbase + k)*PROW]);
            float4 q0 = pv[0], q1 = pv[1], q2 = pv[2], q3 = pv[3], q4 = pv[4];
            f32x2 u0=mk2(q0.x,q0.y), u1=mk2(q0.z,q0.w), u2=mk2(q1.x,q1.y),
                  u3=mk2(q1.z,q1.w), u4=mk2(q2.x,q2.y), u5=mk2(q2.z,q2.w),
                  u6=mk2(q3.x,q3.y), u7=mk2(q3.z,q3.w), u8=mk2(q4.x,q4.y);
            f32x2 d0 = mk2(0.f,0.f), d1 = mk2(0.f,0.f);
            d0 = pk_fma(u0, cp0[0], d0);  d1 = pk_fma(u0, cp1[0], d1);
            d0 = pk_fma(u1, cp0[1], d0);  d1 = pk_fma(u1, cp1[1], d1);
            d0 = pk_fma(u2, cp0[2], d0);  d1 = pk_fma(u2, cp1[2], d1);
            d0 = pk_fma(u3, cp0[3], d0);  d1 = pk_fma(u3, cp1[3], d1);
            d0 = pk_fma(u4, cp0[4], d0);  d1 = pk_fma(u4, cp1[4], d1);
            d0 = pk_fma(u5, cp0[5], d0);  d1 = pk_fma(u5, cp1[5], d1);
            d0 = pk_fma(u6, cp0[6], d0);  d1 = pk_fma(u6, cp1[6], d1);
            d0 = pk_fma(u7, cp0[7], d0);  d1 = pk_fma(u7, cp1[7], d1);
            d0 = pk_fma(u8, cp0[8], d0);  d1 = pk_fma(u8, cp1[8], d1);
            float d20 = fmaf(-2.f, d0.x + d0.y, q4.z + cn20);
            float d21 = fmaf(-2.f, d1.x + d1.y, q4.z + cn21);
            e0[k] = __expf(-__builtin_amdgcn_sqrtf(fmaxf(d20, 1e-12f)));
            e1[k] = __expf(-__builtin_amdgcn_sqrtf(fmaxf(d21, 1e-12f)));
        }

        float s[8];
        {
            const bool hi = (lane & 1);
#pragma unroll
            for (int k = 0; k < 8; ++k) {
                float a  = e0[k]   + e1[k];
                float bq = e0[k+8] + e1[k+8];
                float recv = __shfl_xor(hi ? a : bq, 1);
                s[k] = (hi ? bq : a) + recv;
            }
        }
#define RS_ROUND(MASK, H) { const bool hi = (lane & (MASK)); \
        _Pragma("unroll") \
        for (int k = 0; k < (H); ++k) { \
            float a = s[k], bq = s[k+(H)]; \
            float recv = __shfl_xor(hi ? a : bq, (MASK)); \
            s[k] = (hi ? bq : a) + recv; } }
        RS_ROUND(2, 4)
        RS_ROUND(4, 2)
        RS_ROUND(8, 1)
#undef RS_ROUND
        s[0] += __shfl_xor(s[0], 16);
        s[0] += __shfl_xor(s[0], 32);
        if (lane < 16) ssum_s[t][wv][pxo4] = s[0];
        __syncthreads();
        if (tid < 32) {
            int h = tid >> 4, p4 = tid & 15;
            w_s[t][tid] = 1.0f / (ssum_s[t][2*h][p4] + ssum_s[t][2*h+1][p4]);
        }
        __syncthreads();

#pragma unroll
        for (int k = 0; k < 16; ++k) {
            const float4* pv = reinterpret_cast<const float4*>(
                &pls[(t*PIX + pxbase + k)*PROW]);
            float4 q0 = pv[0], q1 = pv[1], q2 = pv[2], q3 = pv[3], q4 = pv[4];
            float w = w_s[t][pxbase + k];
            float w0 = e0[k]*w, w1 = e1[k]*w;
            f32x2 ew0 = mk2(w0, w0), ew1 = mk2(w1, w1);
            f32x2 u0=mk2(q0.x,q0.y), u1=mk2(q0.z,q0.w), u2=mk2(q1.x,q1.y),
                  u3=mk2(q1.z,q1.w), u4=mk2(q2.x,q2.y), u5=mk2(q2.z,q2.w),
                  u6=mk2(q3.x,q3.y), u7=mk2(q3.z,q3.w), u8=mk2(q4.x,q4.y),
                  u9=mk2(q4.z,q4.w);
            acc0[0] = pk_fma(ew0, u0, acc0[0]);  acc1[0] = pk_fma(ew1, u0, acc1[0]);
            acc0[1] = pk_fma(ew0, u1, acc0[1]);  acc1[1] = pk_fma(ew1, u1, acc1[1]);
            acc0[2] = pk_fma(ew0, u2, acc0[2]);  acc1[2] = pk_fma(ew1, u2, acc1[2]);
            acc0[3] = pk_fma(ew0, u3, acc0[3]);  acc1[3] = pk_fma(ew1, u3, acc1[3]);
            acc0[4] = pk_fma(ew0, u4, acc0[4]);  acc1[4] = pk_fma(ew1, u4, acc1[4]);
            acc0[5] = pk_fma(ew0, u5, acc0[5]);  acc1[5] = pk_fma(ew1, u5, acc1[5]);
            acc0[6] = pk_fma(ew0, u6, acc0[6]);  acc1[6] = pk_fma(ew1, u6, acc1[6]);
            acc0[7] = pk_fma(ew0, u7, acc0[7]);  acc1[7] = pk_fma(ew1, u7, acc1[7]);
            acc0[8] = pk_fma(ew0, u8, acc0[8]);  acc1[8] = pk_fma(ew1, u8, acc1[8]);
            acc0[9] = pk_fma(ew0, u9, acc0[9]);  acc1[9] = pk_fma(ew1, u9, acc1[9]);
        }
    }

    // combine px-half partials across partner threads (tid <-> tid^128)
    if (tid >= 128) {
        float* xb = &xfer[(tid - 128)*41];
#pragma unroll
        for (int j = 0; j < 10; ++j) { xb[2*j]    = acc0[j].x; xb[2*j+1]    = acc0[j].y; }
#pragma unroll
        for (int j = 0; j < 10; ++j) { xb[20+2*j] = acc1[j].x; xb[20+2*j+1] = acc1[j].y; }
    }
    __syncthreads();
    if (tid < 128) {
        const float* xb = &xfer[tid*41];
#pragma unroll
        for (int j = 0; j < 10; ++j) { acc0[j].x += xb[2*j];    acc0[j].y += xb[2*j+1]; }
#pragma unroll
        for (int j = 0; j < 10; ++j) { acc1[j].x += xb[20+2*j]; acc1[j].y += xb[20+2*j+1]; }

        float* dst0 = pp + ((size_t)(b*CHUNKS + chunk)*MM + mlo)*PROW;
        float4* v0 = reinterpret_cast<float4*>(dst0);
        v0[0] = make_float4(acc0[0].x, acc0[0].y, acc0[1].x, acc0[1].y);
        v0[1] = make_float4(acc0[2].x, acc0[2].y, acc0[3].x, acc0[3].y);
        v0[2] = make_float4(acc0[4].x, acc0[4].y, acc0[5].x, acc0[5].y);
        v0[3] = make_float4(acc0[6].x, acc0[6].y, acc0[7].x, acc0[7].y);
        v0[4] = make_float4(acc0[8].x, acc0[8].y, acc0[9].y, 0.f);   // [18]=den

        float* dst1 = pp + ((size_t)(b*CHUNKS + chunk)*MM + mlo + 128)*PROW;
        float4* v1 = reinterpret_cast<float4*>(dst1);
        v1[0] = make_float4(acc1[0].x, acc1[0].y, acc1[1].x, acc1[1].y);
        v1[1] = make_float4(acc1[2].x, acc1[2].y, acc1[3].x, acc1[3].y);
        v1[2] = make_float4(acc1[4].x, acc1[4].y, acc1[5].x, acc1[5].y);
        v1[3] = make_float4(acc1[6].x, acc1[6].y, acc1[7].x, acc1[7].y);
        v1[4] = make_float4(acc1[8].x, acc1[8].y, acc1[9].y, 0.f);
    }
}

// ---------------------------------------------------------------------------
// Final iteration kernel, KM=4 (phase-1 only + Q store; no accumulators so
// VGPR fits 3 waves/EU): lane L of wave wv handles 4 centers
// m = wv*64 + (L>>2) + 16j over 8 pixels px = (L&3) + 4k. LDS reads halved
// vs KM=2 (160 vs 320 b128/thread). Mapping correctness proven in round 10.
// ---------------------------------------------------------------------------
__global__ __launch_bounds__(256, 3)
void ssn_fin(const float* __restrict__ ptbuf, const float* __restrict__ cbuf,
             float* __restrict__ qout)
{
    __shared__ __align__(16) float pls[PIXPERBLK*PROW];   // 10240 B
    __shared__ float ssum_s[TSUB][4][PIX];                //  2048 B
    __shared__ float w_s[TSUB][PIX];                      //   512 B

    const int tid    = threadIdx.x;
    const int b      = blockIdx.x >> 9;
    const int chunk  = blockIdx.x & (CHUNKS-1);
    const int n_base = chunk * PIXPERBLK;
    const int L      = tid & 63;
    const int wv     = tid >> 6;
    const int g      = L & 3;              // px group: px = g + 4k
    const int msub   = L >> 2;             // 0..15
    const int mbase  = wv*64 + msub;       // m_j = mbase + 16*j

    {
        const float4* src = reinterpret_cast<const float4*>(
            ptbuf + (size_t)(b*NN + n_base)*PROW);
#pragma unroll
        for (int k = 0; k < 3; ++k) {
            int f = tid + (k << 8);
            if (f < PIXPERBLK*PROW/4)
                reinterpret_cast<float4*>(pls)[f] = src[f];
        }
    }

    f32x2 cp[4][9]; float cn2[4];
#pragma unroll
    for (int j = 0; j < 4; ++j) {
        const float4* cv = reinterpret_cast<const float4*>(
            cbuf + (b*MM + mbase + 16*j)*CROW);
        float4 a0 = cv[0], a1 = cv[1], a2 = cv[2], a3 = cv[3], a4 = cv[4];
        cp[j][0]=mk2(a0.x,a0.y); cp[j][1]=mk2(a0.z,a0.w);
        cp[j][2]=mk2(a1.x,a1.y); cp[j][3]=mk2(a1.z,a1.w);
        cp[j][4]=mk2(a2.x,a2.y); cp[j][5]=mk2(a2.z,a2.w);
        cp[j][6]=mk2(a3.x,a3.y); cp[j][7]=mk2(a3.z,a3.w);
        cp[j][8]=mk2(a4.x,a4.y); cn2[j]=a4.z;
    }

    __syncthreads();   // pls ready

    for (int t = 0; t < TSUB; ++t) {
        // ---- phase 1: e[j][k]; each row read serves 4 dots ----
        float e[4][8];
#pragma unroll
        for (int k = 0; k < 8; ++k) {
            const int row = t*PIX + g + 4*k;
            const float4* pv = reinterpret_cast<const float4*>(&pls[row*PROW]);
            float4 q0 = pv[0], q1 = pv[1], q2 = pv[2], q3 = pv[3], q4 = pv[4];
            f32x2 u0=mk2(q0.x,q0.y), u1=mk2(q0.z,q0.w), u2=mk2(q1.x,q1.y),
                  u3=mk2(q1.z,q1.w), u4=mk2(q2.x,q2.y), u5=mk2(q2.z,q2.w),
                  u6=mk2(q3.x,q3.y), u7=mk2(q3.z,q3.w), u8=mk2(q4.x,q4.y);
            f32x2 d0=mk2(0.f,0.f), d1=mk2(0.f,0.f), d2v=mk2(0.f,0.f), d3=mk2(0.f,0.f);
            d0 = pk_fma(u0, cp[0][0], d0); d1 = pk_fma(u0, cp[1][0], d1);
            d2v= pk_fma(u0, cp[2][0], d2v);d3 = pk_fma(u0, cp[3][0], d3);
            d0 = pk_fma(u1, cp[0][1], d0); d1 = pk_fma(u1, cp[1][1], d1);
            d2v= pk_fma(u1, cp[2][1], d2v);d3 = pk_fma(u1, cp[3][1], d3);
            d0 = pk_fma(u2, cp[0][2], d0); d1 = pk_fma(u2, cp[1][2], d1);
            d2v= pk_fma(u2, cp[2][2], d2v);d3 = pk_fma(u2, cp[3][2], d3);
            d0 = pk_fma(u3, cp[0][3], d0); d1 = pk_fma(u3, cp[1][3], d1);
            d2v= pk_fma(u3, cp[2][3], d2v);d3 = pk_fma(u3, cp[3][3], d3);
            d0 = pk_fma(u4, cp[0][4], d0); d1 = pk_fma(u4, cp[1][4], d1);
            d2v= pk_fma(u4, cp[2][4], d2v);d3 = pk_fma(u4, cp[3][4], d3);
            d0 = pk_fma(u5, cp[0][5], d0); d1 = pk_fma(u5, cp[1][5], d1);
            d2v= pk_fma(u5, cp[2][5], d2v);d3 = pk_fma(u5, cp[3][5], d3);
            d0 = pk_fma(u6, cp[0][6], d0); d1 = pk_fma(u6, cp[1][6], d1);
            d2v= pk_fma(u6, cp[2][6], d2v);d3 = pk_fma(u6, cp[3][6], d3);
            d0 = pk_fma(u7, cp[0][7], d0); d1 = pk_fma(u7, cp[1][7], d1);
            d2v= pk_fma(u7, cp[2][7], d2v);d3 = pk_fma(u7, cp[3][7], d3);
            d0 = pk_fma(u8, cp[0][8], d0); d1 = pk_fma(u8, cp[1][8], d1);
            d2v= pk_fma(u8, cp[2][8], d2v);d3 = pk_fma(u8, cp[3][8], d3);
            float s0 = fmaf(-2.f, d0.x + d0.y, q4.z + cn2[0]);
            float s1 = fmaf(-2.f, d1.x + d1.y, q4.z + cn2[1]);
            float s2 = fmaf(-2.f, d2v.x + d2v.y, q4.z + cn2[2]);
            float s3 = fmaf(-2.f, d3.x + d3.y, q4.z + cn2[3]);
            e[0][k] = __expf(-__builtin_amdgcn_sqrtf(fmaxf(s0, 1e-12f)));
            e[1][k] = __expf(-__builtin_amdgcn_sqrtf(fmaxf(s1, 1e-12f)));
            e[2][k] = __expf(-__builtin_amdgcn_sqrtf(fmaxf(s2, 1e-12f)));
            e[3][k] = __expf(-__builtin_amdgcn_sqrtf(fmaxf(s3, 1e-12f)));
        }

        // ---- intra-wave softmax partial: 16-lane reduce-scatter over 8 px ----
        float s[8];
#pragma unroll
        for (int k = 0; k < 8; ++k)
            s[k] = (e[0][k] + e[1][k]) + (e[2][k] + e[3][k]);
#define RS_ROUND(MASK, H) { const bool hi = (L & (MASK)); \
        _Pragma("unroll") \
        for (int k = 0; k < (H); ++k) { \
            float a = s[k], bq = s[k+(H)]; \
            float recv = __shfl_xor(hi ? a : bq, (MASK)); \
            s[k] = (hi ? bq : a) + recv; } }
        RS_ROUND(4, 4)
        RS_ROUND(8, 2)
        RS_ROUND(16, 1)
#undef RS_ROUND
        s[0] += __shfl_xor(s[0], 32);
        {
            const int kown = (((L>>2)&1)<<2) | (((L>>3)&1)<<1) | ((L>>4)&1);
            if (L < 32) ssum_s[t][wv][g + 4*kown] = s[0];
        }
        __syncthreads();
        if (tid < 32) {
            w_s[t][tid] = 1.0f / (ssum_s[t][0][tid] + ssum_s[t][1][tid]
                                + ssum_s[t][2][tid] + ssum_s[t][3][tid]);
        }
        __syncthreads();

        // ---- phase 2: Q store only (no LDS rereads) ----
#pragma unroll
        for (int k = 0; k < 8; ++k) {
            float w = w_s[t][g + 4*k];
            size_t rowoff = ((size_t)(b*NN + n_base + t*PIX + g + 4*k)) << 8;
#pragma unroll
            for (int j = 0; j < 4; ++j)
                qout[rowoff + mbase + 16*j] = e[j][k] * w;
        }
    }
}

// ---------------------------------------------------------------------------
// Sum the 512 per-chunk partials for each (b,m); produce new centers row
// (c, ||c||^2) and optionally centers_feat. block=(b,m), thread=chunk low 8b.
// ---------------------------------------------------------------------------
__global__ __launch_bounds__(256)
void reduce_finalize(const float* __restrict__ pp, float* __restrict__ cbuf,
                     float* __restrict__ cfout, int write_cf)
{
    const int b   = blockIdx.x >> 8;
    const int m   = blockIdx.x & 255;
    const int tid = threadIdx.x;
    const int lane = tid & 63, wv = tid >> 6;

    const float4* r0 = reinterpret_cast<const float4*>(
        pp + ((size_t)(b*CHUNKS + tid)*MM + m)*PROW);
    const float4* r1 = reinterpret_cast<const float4*>(
        pp + ((size_t)(b*CHUNKS + tid + 256)*MM + m)*PROW);
    float a[19];
    {
        float4 u0=r0[0], u1=r0[1], u2=r0[2], u3=r0[3], u4=r0[4];
        float4 w0=r1[0], w1=r1[1], w2=r1[2], w3=r1[3], w4=r1[4];
        a[0]=u0.x+w0.x;  a[1]=u0.y+w0.y;  a[2]=u0.z+w0.z;  a[3]=u0.w+w0.w;
        a[4]=u1.x+w1.x;  a[5]=u1.y+w1.y;  a[6]=u1.z+w1.z;  a[7]=u1.w+w1.w;
        a[8]=u2.x+w2.x;  a[9]=u2.y+w2.y;  a[10]=u2.z+w2.z; a[11]=u2.w+w2.w;
        a[12]=u3.x+w3.x; a[13]=u3.y+w3.y; a[14]=u3.z+w3.z; a[15]=u3.w+w3.w;
        a[16]=u4.x+w4.x; a[17]=u4.y+w4.y; a[18]=u4.z+w4.z;
    }
#pragma unroll
    for (int off = 32; off; off >>= 1) {
#pragma unroll
        for (int d = 0; d < 19; ++d) a[d] += __shfl_down(a[d], off);
    }

    __shared__ float red[4][20];
    if (lane == 0) {
#pragma unroll
        for (int d = 0; d < 19; ++d) red[wv][d] = a[d];
    }
    __syncthreads();
    if (tid == 0) {
        float s[19];
#pragma unroll
        for (int d = 0; d < 19; ++d)
            s[d] = red[0][d] + red[1][d] + red[2][d] + red[3][d];
        float den = s[18] + 1e-6f;
        float* row = cbuf + (b*MM + m)*CROW;
        float cn2 = 0.f;
#pragma unroll
        for (int d = 0; d < 18; ++d) {
            float cv = s[d] / den;
            row[d] = cv;
            cn2 = fmaf(cv, cv, cn2);
            if (write_cf && d < 16) cfout[((b*CC + d) << 8) + m] = cv;
        }
        row[18] = cn2;
        row[19] = 0.f;
    }
}

// ---------------------------------------------------------------------------
extern "C" void kernel_launch(void* const* d_in, const int* in_sizes, int n_in,
                              void* d_out, int out_size, void* d_ws, size_t ws_size,
                              hipStream_t stream)
{
    const float* feat = (const float*)d_in[0];
    float* dout = (float*)d_out;

    // d_ws layout: cbuf (128 KB) | ptbuf 21 MB | pp 42 MB
    float* cbuf  = (float*)d_ws;
    float* ptbuf = cbuf + 32768;
    float* pp    = ptbuf + (size_t)BB*NN*PROW;

    float* qout  = dout;                                // [B, N, M]
    float* cfout = dout + (size_t)BB*NN*MM;             // [B, C, M]

    build_pt<<<dim3(BB*256), dim3(256), 0, stream>>>(feat, ptbuf);
    init_centers<<<dim3(BB*MM), dim3(64), 0, stream>>>(feat, cbuf);

    for (int it = 0; it < 2; ++it) {
        ssn_nf<<<dim3(BB*CHUNKS), dim3(256), 0, stream>>>(ptbuf, cbuf, pp);
        reduce_finalize<<<dim3(BB*MM), dim3(256), 0, stream>>>(pp, cbuf, cfout, it == 1);
    }
    ssn_fin<<<dim3(BB*CHUNKS), dim3(256), 0, stream>>>(ptbuf, cbuf, qout);
}